// Round 10
// baseline (362.590 us; speedup 1.0000x reference)
//
#include <hip/hip_runtime.h>

#define DECAYF 0.99f
#define ONEMF 0.01f
#define EPSF 1e-5f

typedef __bf16 bf16x8 __attribute__((ext_vector_type(8)));
typedef float f32x4 __attribute__((ext_vector_type(4)));
typedef unsigned short ushort8 __attribute__((ext_vector_type(8)));

// ws layout (float indices):
// [0,65536)        dw accumulator (K*D)
// [65536,66560)    counts (K)
// [66560,67584)    nchalf = -0.5*||e_k||^2
// [67584]          sse
// [67600,100368)   E_hi as bf16 (ushort), row-major [K][D]
// [100368,133136)  E_lo as bf16 (ushort)
#define WS_COUNTS 65536
#define WS_NCHALF 66560
#define WS_SSE    67584
#define WS_EHI    67600
#define WS_ELO    100368

__device__ __forceinline__ float wave_reduce_add(float v) {
#pragma unroll
    for (int o = 32; o > 0; o >>= 1) v += __shfl_xor(v, o, 64);
    return v;
}

__device__ __forceinline__ unsigned short bf_rne(float f) {
    unsigned int u = __float_as_uint(f);
    unsigned int r = u + 0x7fffu + ((u >> 16) & 1u);
    return (unsigned short)(r >> 16);
}

// Zero dw/counts/sse; split E into bf16 hi/lo; nchalf. grid 256 x 256.
__global__ __launch_bounds__(256) void prep_kernel(const float* __restrict__ E,
                                                   float* __restrict__ ws) {
    const int bid = blockIdx.x, tid = threadIdx.x;
    const int id = bid * 256 + tid;            // element of E (k = id>>6, c = id&63)
    ws[id] = 0.0f;                             // dw
    if (bid < 4) ws[WS_COUNTS + bid * 256 + tid] = 0.0f;
    if (bid == 4 && tid == 0) ws[WS_SSE] = 0.0f;
    const float v = E[id];
    const unsigned short h = bf_rne(v);
    const float hf = __uint_as_float((unsigned int)h << 16);
    const unsigned short l = bf_rne(v - hf);
    ((unsigned short*)(ws + WS_EHI))[id] = h;
    ((unsigned short*)(ws + WS_ELO))[id] = l;
    const int lane = tid & 63;
    const float s = wave_reduce_add(v * v);
    if (lane == 0) ws[WS_NCHALF + (id >> 6)] = -0.5f * s;
}

// Main: MFMA scores + top-2 + fp64 re-rank + all scatter outputs.
// grid 512 x 512; each block = 128 tokens across 8 waves (16 tokens/wave).
// Same tile geometry/traffic as the 256-thread version, but 16 waves/CU
// (4/SIMD) instead of 8 -- the R9 loop was latency-exposed at 2 waves/SIMD
// (ds_read->MFMA->select chains, 64 steps). Per-wave state halves, so
// __launch_bounds__(512,4) caps VGPR at 128 without spills.
__global__ __launch_bounds__(512, 4) void vq_main(const float* __restrict__ x,
                                                  const float* __restrict__ E,
                                                  float* __restrict__ out,
                                                  float* __restrict__ ws) {
    const int tid = threadIdx.x;
    const int lane = tid & 63;
    const int w = tid >> 6;            // 0..7
    const int q = lane >> 4, m = lane & 15;
    const int blk = blockIdx.x;
    const int b = blk >> 5;            // batch
    const int hw0 = (blk & 31) << 7;   // hw offset (128 tokens)
    const int tok0 = blk << 7;

    __shared__ float xs[128 * 68];     // [token][dim], stride 68 keeps rows 16B-aligned
    __shared__ int i1sh[128], i2sh[128], idx_sh[128];
    // Double-buffered 64-code chunk: [hi 8192B][lo 8192B][nchalf 256B].
    __shared__ char lds_b[2][16640];

    float* enc = out + 1 + (size_t)4194304;
    f32x4* encb4 = (f32x4*)(enc + (size_t)tok0 * 1024);   // this block's 512 KB enc region

    const unsigned short* __restrict__ EHIu = (const unsigned short*)(ws + WS_EHI);
    const unsigned short* __restrict__ ELOu = (const unsigned short*)(ws + WS_ELO);
    const float* __restrict__ ncp = ws + WS_NCHALF;

    // Stage x tile (fully coalesced: consecutive tid -> consecutive hw).
    {
        const float* xb = x + ((size_t)b << 18) + hw0;
#pragma unroll
        for (int cc = 0; cc < 16; ++cc) {
            const int id = cc * 512 + tid;
            const int c = id >> 7, t = id & 127;
            xs[t * 68 + c] = xb[((size_t)c << 12) + t];
        }
    }

    // Swizzled LDS destination for this thread's 16B staging unit:
    // unit u = tid (0..511): row cl = u>>3 (0..63), group g = u&7,
    // physical group pg = g ^ (cl&7) -> bank-balanced writes AND reads.
    const int cl_s = tid >> 3, g_s = tid & 7;
    const int dst0 = cl_s * 128 + ((g_s ^ (cl_s & 7)) << 4);

    // Prologue: stage chunk 0 (codes 0..63) directly.
    *(f32x4*)(lds_b[0] + dst0)        = *(const f32x4*)(EHIu + tid * 8);
    *(f32x4*)(lds_b[0] + 8192 + dst0) = *(const f32x4*)(ELOu + tid * 8);
    if (tid < 64) *(float*)(lds_b[0] + 16384 + tid * 4) = ncp[tid];
    __syncthreads();

    // A fragments: 1 row-tile (16 tokens) x 2 K-slices x (hi,lo).
    bf16x8 Ah[2], Al[2];
    {
        const int tok = w * 16 + m;
#pragma unroll
        for (int s = 0; s < 2; ++s) {
            const float* p = &xs[tok * 68 + s * 32 + q * 8];
            ushort8 hu, lu;
#pragma unroll
            for (int j = 0; j < 8; ++j) {
                const float f = p[j];
                const unsigned short h = bf_rne(f);
                const float hf = __uint_as_float((unsigned int)h << 16);
                hu[j] = h;
                lu[j] = bf_rne(f - hf);
            }
            Ah[s] = __builtin_bit_cast(bf16x8, hu);
            Al[s] = __builtin_bit_cast(bf16x8, lu);
        }
    }

    // Per-lane running top-2 per C/D row.
    float b1[4], b2[4];
    int i1[4], i2[4];
#pragma unroll
    for (int r = 0; r < 4; ++r) { b1[r] = -1e30f; b2[r] = -1e30f; i1[r] = 0; i2[r] = 1; }

    const f32x4 z4 = {0.0f, 0.0f, 0.0f, 0.0f};
    const int hm = m & 7;
    const int off0 = (q ^ hm) << 4;           // group q   (dims q*8..)
    const int off1 = ((4 + q) ^ hm) << 4;     // group 4+q (dims 32+q*8..)

    // 16 chunks x 4 steps. Issue-early next-chunk loads + batched NT zero
    // stores at chunk open; ds_write late; barrier WITHOUT vmcnt drain (T4).
    for (int kc = 0; kc < 16; ++kc) {
        f32x4 sH = z4, sL = z4; float sN = 0.0f;
        if (kc < 15) {
            const int eb = (kc + 1) * 4096;
            sH = *(const f32x4*)(EHIu + eb + tid * 8);
            sL = *(const f32x4*)(ELOu + eb + tid * 8);
            if (tid < 64) sN = ncp[(kc + 1) * 64 + tid];
        }
        {   // batched one-hot zero-fill: 4 x 16B NT stores per thread per chunk;
            // 16 chunks x 2048 slots x 16B = this block's 128 enc rows exactly.
            const int zslot = kc * 2048 + tid;
            __builtin_nontemporal_store(z4, encb4 + zslot);
            __builtin_nontemporal_store(z4, encb4 + zslot + 512);
            __builtin_nontemporal_store(z4, encb4 + zslot + 1024);
            __builtin_nontemporal_store(z4, encb4 + zslot + 1536);
        }
        const char* bufc = lds_b[kc & 1];

#define VQ_STEP(S)                                                              \
    {                                                                           \
        const int cl = (S) * 16 + m;                                            \
        const char* rowp = bufc + cl * 128;                                     \
        const bf16x8 bh0 = *(const bf16x8*)(rowp + off0);                       \
        const bf16x8 bh1 = *(const bf16x8*)(rowp + off1);                       \
        const bf16x8 bl0 = *(const bf16x8*)(rowp + 8192 + off0);                \
        const bf16x8 bl1 = *(const bf16x8*)(rowp + 8192 + off1);                \
        const float nc = *(const float*)(bufc + 16384 + cl * 4);                \
        const int idx = kc * 64 + cl;                                           \
        f32x4 acc = {nc, nc, nc, nc}; /* score = x.e - 0.5||e||^2 */            \
        acc = __builtin_amdgcn_mfma_f32_16x16x32_bf16(Ah[0], bh0, acc, 0, 0, 0);\
        acc = __builtin_amdgcn_mfma_f32_16x16x32_bf16(Ah[1], bh1, acc, 0, 0, 0);\
        acc = __builtin_amdgcn_mfma_f32_16x16x32_bf16(Al[0], bh0, acc, 0, 0, 0);\
        acc = __builtin_amdgcn_mfma_f32_16x16x32_bf16(Al[1], bh1, acc, 0, 0, 0);\
        acc = __builtin_amdgcn_mfma_f32_16x16x32_bf16(Ah[0], bl0, acc, 0, 0, 0);\
        acc = __builtin_amdgcn_mfma_f32_16x16x32_bf16(Ah[1], bl1, acc, 0, 0, 0);\
        _Pragma("unroll")                                                       \
        for (int r = 0; r < 4; ++r) {                                           \
            const float s = acc[r];                                             \
            const bool cA = s > b1[r];                                          \
            const bool cB = s > b2[r];                                          \
            b2[r] = cA ? b1[r] : (cB ? s : b2[r]);                              \
            i2[r] = cA ? i1[r] : (cB ? idx : i2[r]);                            \
            b1[r] = cA ? s : b1[r];                                             \
            i1[r] = cA ? idx : i1[r];                                           \
        }                                                                       \
    }

        VQ_STEP(0)
        VQ_STEP(1)
        VQ_STEP(2)
        VQ_STEP(3)
#undef VQ_STEP

        if (kc < 15) {
            char* bufn = lds_b[(kc + 1) & 1];
            *(f32x4*)(bufn + dst0)        = sH;   // counted vmcnt here (reg dep);
            *(f32x4*)(bufn + 8192 + dst0) = sL;   // NT stores stay in flight
            if (tid < 64) *(float*)(bufn + 16384 + tid * 4) = sN;
        }
        // Barrier WITHOUT vmcnt(0): order LDS ops only.
        asm volatile("s_waitcnt lgkmcnt(0)" ::: "memory");
        __builtin_amdgcn_s_barrier();
        __builtin_amdgcn_sched_barrier(0);
    }

    // Merge top-2 across the 16 lanes of each quad-group (cols of the row).
#pragma unroll
    for (int d = 1; d < 16; d <<= 1) {
#pragma unroll
        for (int r = 0; r < 4; ++r) {
            const float ob1 = __shfl_xor(b1[r], d, 64);
            const int   oi1 = __shfl_xor(i1[r], d, 64);
            const float ob2 = __shfl_xor(b2[r], d, 64);
            const int   oi2 = __shfl_xor(i2[r], d, 64);
            const bool wv = ob1 > b1[r];
            const float t1 = wv ? ob1 : b1[r]; const int ti1 = wv ? oi1 : i1[r];
            const float sA = wv ? b1[r] : ob1; const int siA = wv ? i1[r] : oi1;
            const float sB = wv ? ob2 : b2[r]; const int siB = wv ? oi2 : i2[r];
            const bool w2 = sB > sA;
            b1[r] = t1; i1[r] = ti1;
            b2[r] = w2 ? sB : sA; i2[r] = w2 ? siB : siA;
        }
    }
    if (m == 0) {   // quad leaders publish rows 4q+r of this wave's tile
#pragma unroll
        for (int r = 0; r < 4; ++r) {
            const int tokL = w * 16 + q * 4 + r;
            i1sh[tokL] = i1[r];
            i2sh[tokL] = i2[r];
        }
    }

    // fp64 re-rank of the two candidates (same wave -> no barrier needed).
    float dval = 0.0f;
    if (lane < 16) {
        const int tokL = w * 16 + lane;
        const int I1 = i1sh[tokL], I2 = i2sh[tokL];
        const int ca = I1 < I2 ? I1 : I2;
        const int cb = I1 < I2 ? I2 : I1;
        const float* Ea = E + ca * 64;
        const float* Eb = E + cb * 64;
        const float* xr = &xs[tokL * 68];
        double sa = 0, ea = 0, sb = 0, eb = 0, x2 = 0;
#pragma unroll 8
        for (int c = 0; c < 64; ++c) {
            const double xv = (double)xr[c];
            const double va = (double)Ea[c], vb = (double)Eb[c];
            sa += xv * va; ea += va * va;
            sb += xv * vb; eb += vb * vb;
            x2 += xv * xv;
        }
        const double qa = ea - 2.0 * sa;
        const double qb = eb - 2.0 * sb;
        int best; double qq;
        if (qb < qa) { best = cb; qq = qb; } else { best = ca; qq = qa; }
        idx_sh[tokL] = best;
        float dd = (float)(qq + x2);
        dval = dd < 0.f ? 0.f : dd;
        atomicAdd(&ws[WS_COUNTS + best], 1.0f);
    }
    const float ssum = wave_reduce_add(dval);
    if (lane == 0) atomicAdd(&ws[WS_SSE], ssum);
    __syncthreads();   // FULL drain (vmcnt(0)): zero stores retire before 1.0 writes

    // q_st output (reference order: x + (e - x)).
    float* outq = out + 1;
#pragma unroll
    for (int cc = 0; cc < 16; ++cc) {
        const int id = cc * 512 + tid;
        const int c = id >> 7, t = id & 127;
        const int kb = idx_sh[t];
        const float xv = xs[t * 68 + c];
        const float eq = E[kb * 64 + c];
        outq[((size_t)(b * 64 + c) << 12) + hw0 + t] = xv + (eq - xv);
    }
    // dw scatter-add: lane = dim (coalesced atomics), wave-uniform row.
#pragma unroll 4
    for (int tt = 0; tt < 16; ++tt) {
        const int t = w * 16 + tt;
        const int kb = idx_sh[t];
        atomicAdd(&ws[kb * 64 + lane], xs[t * 68 + lane]);
    }
    // one-hot encodings: rows pre-zeroed in the K-loop; write only the 1.0 entries.
    {
        if (tid < 128) {
            const int kb = idx_sh[tid];
            __builtin_nontemporal_store(1.0f, enc + (size_t)(tok0 + tid) * 1024 + kb);
        }
    }
}

// new_cs (Laplace-smoothed) + loss. 1 block x 1024.
__global__ __launch_bounds__(1024) void fin_cs(const float* __restrict__ cs_in,
                                               float* __restrict__ out,
                                               const float* __restrict__ ws) {
    __shared__ float red[16];
    __shared__ float n_sh;
    const int tid = threadIdx.x;
    const float raw = cs_in[tid] * DECAYF + ONEMF * ws[WS_COUNTS + tid];
    const float s = wave_reduce_add(raw);
    if ((tid & 63) == 0) red[tid >> 6] = s;
    __syncthreads();
    if (tid == 0) {
        float n = 0.f;
#pragma unroll
        for (int i = 0; i < 16; ++i) n += red[i];
        n_sh = n;
        out[0] = 0.25f * ws[WS_SSE] * (1.0f / 4194304.0f);  // loss
    }
    __syncthreads();
    const float n = n_sh;
    out[71368705 + tid] = (raw + EPSF) / (n + 1024.0f * EPSF) * n;
}

// new_ema_weight and new_embedding. grid 256 x 256.
__global__ __launch_bounds__(256) void fin_w(const float* __restrict__ emaw,
                                             float* __restrict__ out,
                                             const float* __restrict__ ws) {
    const int i = blockIdx.x * 256 + threadIdx.x;
    const float val = emaw[i] * DECAYF + ONEMF * ws[i];
    out[71369729 + i] = val;                               // new_ema_weight
    const float cs = out[71368705 + (i >> 6)];             // new_cs (from fin_cs)
    out[71303169 + i] = val / cs;                          // new_embedding
}

extern "C" void kernel_launch(void* const* d_in, const int* in_sizes, int n_in,
                              void* d_out, int out_size, void* d_ws, size_t ws_size,
                              hipStream_t stream) {
    const float* x    = (const float*)d_in[0];   // [16,64,64,64]
    const float* E    = (const float*)d_in[1];   // [1024,64]
    const float* cs   = (const float*)d_in[2];   // [1024]
    const float* emaw = (const float*)d_in[3];   // [1024,64]
    float* out = (float*)d_out;
    float* ws  = (float*)d_ws;

    prep_kernel<<<256, 256, 0, stream>>>(E, ws);
    vq_main<<<512, 512, 0, stream>>>(x, E, out, ws);
    fin_cs<<<1, 1024, 0, stream>>>(cs, out, ws);
    fin_w<<<256, 256, 0, stream>>>(emaw, out, ws);
}

// Round 11
// 345.869 us; speedup vs baseline: 1.0483x; 1.0483x over previous
//
#include <hip/hip_runtime.h>

#define DECAYF 0.99f
#define ONEMF 0.01f
#define EPSF 1e-5f

typedef __bf16 bf16x8 __attribute__((ext_vector_type(8)));
typedef float f32x4 __attribute__((ext_vector_type(4)));
typedef unsigned short ushort8 __attribute__((ext_vector_type(8)));

// ws layout (float indices):
// [0,65536)        dw accumulator (K*D)
// [65536,66560)    counts (K)
// [66560,67584)    nchalf = -0.5*||e_k||^2
// [67584]          sse
// [67600,100368)   E_hi as bf16 (ushort), row-major [K][D]
// [100368,133136)  E_lo as bf16 (ushort)
#define WS_COUNTS 65536
#define WS_NCHALF 66560
#define WS_SSE    67584
#define WS_EHI    67600
#define WS_ELO    100368

__device__ __forceinline__ float wave_reduce_add(float v) {
#pragma unroll
    for (int o = 32; o > 0; o >>= 1) v += __shfl_xor(v, o, 64);
    return v;
}

__device__ __forceinline__ unsigned short bf_rne(float f) {
    unsigned int u = __float_as_uint(f);
    unsigned int r = u + 0x7fffu + ((u >> 16) & 1u);
    return (unsigned short)(r >> 16);
}

// Zero dw/counts/sse; split E into bf16 hi/lo; nchalf. grid 256 x 256.
__global__ __launch_bounds__(256) void prep_kernel(const float* __restrict__ E,
                                                   float* __restrict__ ws) {
    const int bid = blockIdx.x, tid = threadIdx.x;
    const int id = bid * 256 + tid;            // element of E (k = id>>6, c = id&63)
    ws[id] = 0.0f;                             // dw
    if (bid < 4) ws[WS_COUNTS + bid * 256 + tid] = 0.0f;
    if (bid == 4 && tid == 0) ws[WS_SSE] = 0.0f;
    const float v = E[id];
    const unsigned short h = bf_rne(v);
    const float hf = __uint_as_float((unsigned int)h << 16);
    const unsigned short l = bf_rne(v - hf);
    ((unsigned short*)(ws + WS_EHI))[id] = h;
    ((unsigned short*)(ws + WS_ELO))[id] = l;
    const int lane = tid & 63;
    const float s = wave_reduce_add(v * v);
    if (lane == 0) ws[WS_NCHALF + (id >> 6)] = -0.5f * s;
}

// Main: MFMA scores + top-2 + fp64 re-rank + all scatter outputs.
// grid 512 x 256; each block = 128 tokens (R9 config -- best measured).
// B staged via LDS in 64-code double-buffered chunks (XOR-swizzled rows);
// in-loop barriers are raw s_barrier + lgkmcnt(0) (no vmcnt drain, T4).
// R11 change: tail coalesced -- 1.0 stores issued first, quantized E rows
// staged as coalesced 64-lane row reads into LDS (aliasing the dead B buffer),
// q_st reads LDS and streams out with NT stores. Removes 8192 scattered 4B
// gathers per block that were fully latency-exposed after the drain barrier.
__global__ __launch_bounds__(256, 2) void vq_main(const float* __restrict__ x,
                                                  const float* __restrict__ E,
                                                  float* __restrict__ out,
                                                  float* __restrict__ ws) {
    const int tid = threadIdx.x;
    const int lane = tid & 63;
    const int w = tid >> 6;
    const int q = lane >> 4, m = lane & 15;
    const int blk = blockIdx.x;
    const int b = blk >> 5;            // batch
    const int hw0 = (blk & 31) << 7;   // hw offset (128 tokens)
    const int tok0 = blk << 7;

    __shared__ float xs[128 * 68];     // [token][dim], stride 68 keeps rows 16B-aligned
    __shared__ int i1sh[128], i2sh[128], idx_sh[128];
    // Double-buffered 64-code chunk: [hi 8192B][lo 8192B][nchalf 256B].
    // After the K-loop this space is reused as eqb[128][65] (33280B needed).
    __shared__ char lds_b[2][16640];

    float* enc = out + 1 + (size_t)4194304;
    f32x4* encb4 = (f32x4*)(enc + (size_t)tok0 * 1024);   // this block's 512 KB enc region

    const unsigned short* __restrict__ EHIu = (const unsigned short*)(ws + WS_EHI);
    const unsigned short* __restrict__ ELOu = (const unsigned short*)(ws + WS_ELO);
    const float* __restrict__ ncp = ws + WS_NCHALF;

    // Stage x tile (fully coalesced: consecutive tid -> consecutive hw).
    {
        const float* xb = x + ((size_t)b << 18) + hw0;
#pragma unroll
        for (int cc = 0; cc < 32; ++cc) {
            const int id = cc * 256 + tid;
            const int c = id >> 7, t = id & 127;
            xs[t * 68 + c] = xb[((size_t)c << 12) + t];
        }
    }

    // Swizzled LDS destinations for this thread's two 16B staging units:
    // unit u: row cl = u>>3 (0..63), group g = u&7, phys pg = g ^ (cl&7).
    const int cl_s = tid >> 3, g_s = tid & 7;
    const int dst0 = cl_s * 128 + ((g_s ^ (cl_s & 7)) << 4);

    // Prologue: stage chunk 0 (codes 0..63) directly.
    *(f32x4*)(lds_b[0] + dst0)               = *(const f32x4*)(EHIu + tid * 8);
    *(f32x4*)(lds_b[0] + dst0 + 4096)        = *(const f32x4*)(EHIu + (tid + 256) * 8);
    *(f32x4*)(lds_b[0] + 8192 + dst0)        = *(const f32x4*)(ELOu + tid * 8);
    *(f32x4*)(lds_b[0] + 8192 + dst0 + 4096) = *(const f32x4*)(ELOu + (tid + 256) * 8);
    if (tid < 64) *(float*)(lds_b[0] + 16384 + tid * 4) = ncp[tid];
    __syncthreads();

    // A fragments: 2 row-tiles (16 tokens each) x 2 K-slices x (hi,lo).
    bf16x8 Ah[2][2], Al[2][2];
#pragma unroll
    for (int t = 0; t < 2; ++t) {
        const int tok = w * 32 + t * 16 + m;
#pragma unroll
        for (int s = 0; s < 2; ++s) {
            const float* p = &xs[tok * 68 + s * 32 + q * 8];
            ushort8 hu, lu;
#pragma unroll
            for (int j = 0; j < 8; ++j) {
                const float f = p[j];
                const unsigned short h = bf_rne(f);
                const float hf = __uint_as_float((unsigned int)h << 16);
                hu[j] = h;
                lu[j] = bf_rne(f - hf);
            }
            Ah[t][s] = __builtin_bit_cast(bf16x8, hu);
            Al[t][s] = __builtin_bit_cast(bf16x8, lu);
        }
    }

    // Per-lane running top-2 per C/D row (4 regs x 2 tiles).
    float b1[2][4], b2[2][4];
    int i1[2][4], i2[2][4];
#pragma unroll
    for (int t = 0; t < 2; ++t)
#pragma unroll
        for (int r = 0; r < 4; ++r) { b1[t][r] = -1e30f; b2[t][r] = -1e30f; i1[t][r] = 0; i2[t][r] = 1; }

    const f32x4 z4 = {0.0f, 0.0f, 0.0f, 0.0f};
    const int hm = m & 7;
    const int off0 = (q ^ hm) << 4;           // group q   (dims q*8..)
    const int off1 = ((4 + q) ^ hm) << 4;     // group 4+q (dims 32+q*8..)

    // 16 chunks x 4 steps. Issue-early next-chunk loads + batched NT zero
    // stores at chunk open; ds_write late; barrier WITHOUT vmcnt drain (T4).
    for (int kc = 0; kc < 16; ++kc) {
        f32x4 sH0 = z4, sH1 = z4, sL0 = z4, sL1 = z4; float sN = 0.0f;
        if (kc < 15) {
            const int eb = (kc + 1) * 4096;
            sH0 = *(const f32x4*)(EHIu + eb + tid * 8);
            sH1 = *(const f32x4*)(EHIu + eb + (tid + 256) * 8);
            sL0 = *(const f32x4*)(ELOu + eb + tid * 8);
            sL1 = *(const f32x4*)(ELOu + eb + (tid + 256) * 8);
            if (tid < 64) sN = ncp[(kc + 1) * 64 + tid];
        }
        {   // batched one-hot zero-fill: 4 x 16B NT stores per thread per chunk;
            // 16 chunks x 2048 x 16B = this block's 128 enc rows exactly.
            const int zslot = kc * 2048 + tid;
            __builtin_nontemporal_store(z4, encb4 + zslot);
            __builtin_nontemporal_store(z4, encb4 + zslot + 512);
            __builtin_nontemporal_store(z4, encb4 + zslot + 1024);
            __builtin_nontemporal_store(z4, encb4 + zslot + 1536);
        }
        const char* bufc = lds_b[kc & 1];

#define VQ_STEP(S)                                                              \
    {                                                                           \
        const int cl = (S) * 16 + m;                                            \
        const char* rowp = bufc + cl * 128;                                     \
        const bf16x8 bh0 = *(const bf16x8*)(rowp + off0);                       \
        const bf16x8 bh1 = *(const bf16x8*)(rowp + off1);                       \
        const bf16x8 bl0 = *(const bf16x8*)(rowp + 8192 + off0);                \
        const bf16x8 bl1 = *(const bf16x8*)(rowp + 8192 + off1);                \
        const float nc = *(const float*)(bufc + 16384 + cl * 4);                \
        const int idx = kc * 64 + cl;                                           \
        _Pragma("unroll")                                                       \
        for (int t = 0; t < 2; ++t) {                                           \
            f32x4 acc = {nc, nc, nc, nc}; /* score = x.e - 0.5||e||^2 */        \
            acc = __builtin_amdgcn_mfma_f32_16x16x32_bf16(Ah[t][0], bh0, acc, 0, 0, 0); \
            acc = __builtin_amdgcn_mfma_f32_16x16x32_bf16(Ah[t][1], bh1, acc, 0, 0, 0); \
            acc = __builtin_amdgcn_mfma_f32_16x16x32_bf16(Al[t][0], bh0, acc, 0, 0, 0); \
            acc = __builtin_amdgcn_mfma_f32_16x16x32_bf16(Al[t][1], bh1, acc, 0, 0, 0); \
            acc = __builtin_amdgcn_mfma_f32_16x16x32_bf16(Ah[t][0], bl0, acc, 0, 0, 0); \
            acc = __builtin_amdgcn_mfma_f32_16x16x32_bf16(Ah[t][1], bl1, acc, 0, 0, 0); \
            _Pragma("unroll")                                                   \
            for (int r = 0; r < 4; ++r) {                                       \
                const float s = acc[r];                                         \
                const bool cA = s > b1[t][r];                                   \
                const bool cB = s > b2[t][r];                                   \
                b2[t][r] = cA ? b1[t][r] : (cB ? s : b2[t][r]);                 \
                i2[t][r] = cA ? i1[t][r] : (cB ? idx : i2[t][r]);               \
                b1[t][r] = cA ? s : b1[t][r];                                   \
                i1[t][r] = cA ? idx : i1[t][r];                                 \
            }                                                                   \
        }                                                                       \
    }

        VQ_STEP(0)
        VQ_STEP(1)
        VQ_STEP(2)
        VQ_STEP(3)
#undef VQ_STEP

        if (kc < 15) {
            char* bufn = lds_b[(kc + 1) & 1];
            *(f32x4*)(bufn + dst0)               = sH0;   // counted vmcnt here (reg
            *(f32x4*)(bufn + dst0 + 4096)        = sH1;   // dep); NT stores stay in
            *(f32x4*)(bufn + 8192 + dst0)        = sL0;   // flight across chunks
            *(f32x4*)(bufn + 8192 + dst0 + 4096) = sL1;
            if (tid < 64) *(float*)(bufn + 16384 + tid * 4) = sN;
        }
        // Barrier WITHOUT vmcnt(0): order LDS ops only.
        asm volatile("s_waitcnt lgkmcnt(0)" ::: "memory");
        __builtin_amdgcn_s_barrier();
        __builtin_amdgcn_sched_barrier(0);
    }

    // Merge top-2 across the 16 lanes of each quad-group (cols of the row).
#pragma unroll
    for (int d = 1; d < 16; d <<= 1) {
#pragma unroll
        for (int t = 0; t < 2; ++t)
#pragma unroll
            for (int r = 0; r < 4; ++r) {
                const float ob1 = __shfl_xor(b1[t][r], d, 64);
                const int   oi1 = __shfl_xor(i1[t][r], d, 64);
                const float ob2 = __shfl_xor(b2[t][r], d, 64);
                const int   oi2 = __shfl_xor(i2[t][r], d, 64);
                const bool wv = ob1 > b1[t][r];
                const float t1 = wv ? ob1 : b1[t][r]; const int ti1 = wv ? oi1 : i1[t][r];
                const float sA = wv ? b1[t][r] : ob1; const int siA = wv ? i1[t][r] : oi1;
                const float sB = wv ? ob2 : b2[t][r]; const int siB = wv ? oi2 : i2[t][r];
                const bool w2 = sB > sA;
                b1[t][r] = t1; i1[t][r] = ti1;
                b2[t][r] = w2 ? sB : sA; i2[t][r] = w2 ? siB : siA;
            }
    }
    if (m == 0) {   // quad leaders publish rows 4q+r of each tile
#pragma unroll
        for (int t = 0; t < 2; ++t)
#pragma unroll
            for (int r = 0; r < 4; ++r) {
                const int tokL = w * 32 + t * 16 + q * 4 + r;
                i1sh[tokL] = i1[t][r];
                i2sh[tokL] = i2[t][r];
            }
    }

    // fp64 re-rank of the two candidates (same wave -> no barrier needed).
    float dval = 0.0f;
    if (lane < 32) {
        const int tokL = w * 32 + lane;
        const int I1 = i1sh[tokL], I2 = i2sh[tokL];
        const int ca = I1 < I2 ? I1 : I2;
        const int cb = I1 < I2 ? I2 : I1;
        const float* Ea = E + ca * 64;
        const float* Eb = E + cb * 64;
        const float* xr = &xs[tokL * 68];
        double sa = 0, ea = 0, sb = 0, eb = 0, x2 = 0;
#pragma unroll 8
        for (int c = 0; c < 64; ++c) {
            const double xv = (double)xr[c];
            const double va = (double)Ea[c], vb = (double)Eb[c];
            sa += xv * va; ea += va * va;
            sb += xv * vb; eb += vb * vb;
            x2 += xv * xv;
        }
        const double qa = ea - 2.0 * sa;
        const double qb = eb - 2.0 * sb;
        int best; double qq;
        if (qb < qa) { best = cb; qq = qb; } else { best = ca; qq = qa; }
        idx_sh[tokL] = best;
        float dd = (float)(qq + x2);
        dval = dd < 0.f ? 0.f : dd;
        atomicAdd(&ws[WS_COUNTS + best], 1.0f);
    }
    const float ssum = wave_reduce_add(dval);
    if (lane == 0) atomicAdd(&ws[WS_SSE], ssum);
    __syncthreads();   // FULL drain (vmcnt(0)): zero stores retired before 1.0 writes

    // 1.0 enc entries first (fire-and-forget; drain under the rest of the tail).
    if (tid < 128) {
        const int kb = idx_sh[tid];
        __builtin_nontemporal_store(1.0f, enc + (size_t)(tok0 + tid) * 1024 + kb);
    }

    // Stage quantized rows coalesced: wave w copies rows idx_sh[w*32..+31],
    // 64-lane row reads (2 cache lines each) into eqb (aliasing dead lds_b).
    float* eqb = (float*)lds_b;       // [128][65], 33280B <= sizeof(lds_b)
#pragma unroll
    for (int j = 0; j < 32; ++j) {
        const int t = w * 32 + j;
        eqb[t * 65 + lane] = E[idx_sh[t] * 64 + lane];
    }
    asm volatile("s_waitcnt lgkmcnt(0)" ::: "memory");
    __builtin_amdgcn_s_barrier();     // LDS-only barrier (no vmcnt drain)

    // q_st output (reference order: x + (e - x)); NT stores (pure streaming).
    float* outq = out + 1;
#pragma unroll
    for (int cc = 0; cc < 32; ++cc) {
        const int id = cc * 256 + tid;
        const int c = id >> 7, t = id & 127;
        const float xv = xs[t * 68 + c];
        const float eq = eqb[t * 65 + c];
        __builtin_nontemporal_store(xv + (eq - xv),
                                    outq + ((size_t)(b * 64 + c) << 12) + hw0 + t);
    }
    // dw scatter-add: lane = dim (coalesced atomics), wave-uniform row.
#pragma unroll 4
    for (int tt = 0; tt < 32; ++tt) {
        const int t = w * 32 + tt;
        const int kb = idx_sh[t];
        atomicAdd(&ws[kb * 64 + lane], xs[t * 68 + lane]);
    }
}

// new_cs (Laplace-smoothed) + loss. 1 block x 1024.
__global__ __launch_bounds__(1024) void fin_cs(const float* __restrict__ cs_in,
                                               float* __restrict__ out,
                                               const float* __restrict__ ws) {
    __shared__ float red[16];
    __shared__ float n_sh;
    const int tid = threadIdx.x;
    const float raw = cs_in[tid] * DECAYF + ONEMF * ws[WS_COUNTS + tid];
    const float s = wave_reduce_add(raw);
    if ((tid & 63) == 0) red[tid >> 6] = s;
    __syncthreads();
    if (tid == 0) {
        float n = 0.f;
#pragma unroll
        for (int i = 0; i < 16; ++i) n += red[i];
        n_sh = n;
        out[0] = 0.25f * ws[WS_SSE] * (1.0f / 4194304.0f);  // loss
    }
    __syncthreads();
    const float n = n_sh;
    out[71368705 + tid] = (raw + EPSF) / (n + 1024.0f * EPSF) * n;
}

// new_ema_weight and new_embedding. grid 256 x 256.
__global__ __launch_bounds__(256) void fin_w(const float* __restrict__ emaw,
                                             float* __restrict__ out,
                                             const float* __restrict__ ws) {
    const int i = blockIdx.x * 256 + threadIdx.x;
    const float val = emaw[i] * DECAYF + ONEMF * ws[i];
    out[71369729 + i] = val;                               // new_ema_weight
    const float cs = out[71368705 + (i >> 6)];             // new_cs (from fin_cs)
    out[71303169 + i] = val / cs;                          // new_embedding
}

extern "C" void kernel_launch(void* const* d_in, const int* in_sizes, int n_in,
                              void* d_out, int out_size, void* d_ws, size_t ws_size,
                              hipStream_t stream) {
    const float* x    = (const float*)d_in[0];   // [16,64,64,64]
    const float* E    = (const float*)d_in[1];   // [1024,64]
    const float* cs   = (const float*)d_in[2];   // [1024]
    const float* emaw = (const float*)d_in[3];   // [1024,64]
    float* out = (float*)d_out;
    float* ws  = (float*)d_ws;

    prep_kernel<<<256, 256, 0, stream>>>(E, ws);
    vq_main<<<512, 256, 0, stream>>>(x, E, out, ws);
    fin_cs<<<1, 1024, 0, stream>>>(cs, out, ws);
    fin_w<<<256, 256, 0, stream>>>(emaw, out, ws);
}